// Round 1
// baseline (256.288 us; speedup 1.0000x reference)
//
#include <hip/hip_runtime.h>
#include <hip/hip_bf16.h>

typedef _Float16 f16x8 __attribute__((ext_vector_type(8)));
typedef _Float16 f16x4 __attribute__((ext_vector_type(4)));
typedef float f32x4 __attribute__((ext_vector_type(4)));

__device__ __forceinline__ void async_ld16(_Float16* lds, const _Float16* g) {
    __builtin_amdgcn_global_load_lds(
        (const __attribute__((address_space(1))) void*)g,
        (__attribute__((address_space(3))) void*)lds, 16, 0, 0);
}

// C[M,N] = A[M,K] * B[N,K]^T   (both operands k-contiguous, fp16 -> fp32)
// 128x128 block tile, 4 waves in 2x2, each wave 64x64 via 4x4 grid of 16x16x32 MFMA.
__global__ __launch_bounds__(256) void gemm_bt(
    const _Float16* __restrict__ A,
    const _Float16* __restrict__ B,
    float* __restrict__ C,
    int M, int N, int K)
{
    __shared__ _Float16 At[128 * 32];
    __shared__ _Float16 Bt[128 * 32];

    const int tid  = threadIdx.x;
    const int wave = tid >> 6;
    const int lane = tid & 63;
    const int row0 = blockIdx.y * 128;
    const int col0 = blockIdx.x * 128;
    const int wr = (wave >> 1) * 64;
    const int wc = (wave & 1) * 64;
    const int quad = lane >> 4;
    const int l16  = lane & 15;

    f32x4 acc[4][4] = {};

    // staging: chunk c (0..7) covers LDS rows c*16..c*16+15 (row = 32 fp16 = 64B).
    // wave w stages chunks w and w+4. lane l -> row c*16 + l/4, k-off (l&3)*8.
    const int srow = lane >> 2;
    const int skoff = (lane & 3) * 8;
    const _Float16* Ab = A + (size_t)row0 * K;
    const _Float16* Bb = B + (size_t)col0 * K;

    for (int k0 = 0; k0 < K; k0 += 32) {
        async_ld16(At + wave * 512,       Ab + (size_t)(wave * 16      + srow) * K + k0 + skoff);
        async_ld16(At + (wave + 4) * 512, Ab + (size_t)(wave * 16 + 64 + srow) * K + k0 + skoff);
        async_ld16(Bt + wave * 512,       Bb + (size_t)(wave * 16      + srow) * K + k0 + skoff);
        async_ld16(Bt + (wave + 4) * 512, Bb + (size_t)(wave * 16 + 64 + srow) * K + k0 + skoff);
        __syncthreads();

        f16x8 af[4], bf[4];
        #pragma unroll
        for (int r = 0; r < 4; ++r)
            af[r] = *(const f16x8*)&At[(wr + r * 16 + l16) * 32 + quad * 8];
        #pragma unroll
        for (int c = 0; c < 4; ++c)
            bf[c] = *(const f16x8*)&Bt[(wc + c * 16 + l16) * 32 + quad * 8];

        #pragma unroll
        for (int r = 0; r < 4; ++r)
            #pragma unroll
            for (int c = 0; c < 4; ++c)
                acc[r][c] = __builtin_amdgcn_mfma_f32_16x16x32_f16(af[r], bf[c], acc[r][c], 0, 0, 0);
        __syncthreads();
    }

    // C/D layout: col = lane&15, row = quad*4 + reg   [verified m89/m91]
    #pragma unroll
    for (int r = 0; r < 4; ++r) {
        const int growb = row0 + wr + r * 16 + quad * 4;
        #pragma unroll
        for (int c = 0; c < 4; ++c) {
            const int gcol = col0 + wc + c * 16 + l16;
            #pragma unroll
            for (int i = 0; i < 4; ++i)
                C[(size_t)(growb + i) * N + gcol] = acc[r][c][i];
        }
    }
}

// one block (256 thr) per row of S [rows x 4096]; P = softmax(S)*scale in fp16
__global__ __launch_bounds__(256) void softmax_rows(
    const float* __restrict__ S, _Float16* __restrict__ P, float scale)
{
    __shared__ float red[4];
    const int row = blockIdx.x;
    const int tid = threadIdx.x;
    const int wave = tid >> 6;
    const float4* Sr = (const float4*)(S + (size_t)row * 4096);

    float4 x[4];
    #pragma unroll
    for (int i = 0; i < 4; ++i) x[i] = Sr[tid + i * 256];

    float mx = -3.402823466e+38f;
    #pragma unroll
    for (int i = 0; i < 4; ++i) {
        mx = fmaxf(mx, fmaxf(fmaxf(x[i].x, x[i].y), fmaxf(x[i].z, x[i].w)));
    }
    #pragma unroll
    for (int off = 32; off > 0; off >>= 1) mx = fmaxf(mx, __shfl_down(mx, off));
    if ((tid & 63) == 0) red[wave] = mx;
    __syncthreads();
    mx = fmaxf(fmaxf(red[0], red[1]), fmaxf(red[2], red[3]));
    __syncthreads();

    float sum = 0.0f;
    #pragma unroll
    for (int i = 0; i < 4; ++i) {
        x[i].x = __expf(x[i].x - mx);
        x[i].y = __expf(x[i].y - mx);
        x[i].z = __expf(x[i].z - mx);
        x[i].w = __expf(x[i].w - mx);
        sum += x[i].x + x[i].y + x[i].z + x[i].w;
    }
    #pragma unroll
    for (int off = 32; off > 0; off >>= 1) sum += __shfl_down(sum, off);
    if ((tid & 63) == 0) red[wave] = sum;
    __syncthreads();
    sum = red[0] + red[1] + red[2] + red[3];

    const float inv = scale / sum;
    f16x4* Pr = (f16x4*)(P + (size_t)row * 4096);
    #pragma unroll
    for (int i = 0; i < 4; ++i) {
        f16x4 h;
        h.x = (_Float16)(x[i].x * inv);
        h.y = (_Float16)(x[i].y * inv);
        h.z = (_Float16)(x[i].z * inv);
        h.w = (_Float16)(x[i].w * inv);
        Pr[tid + i * 256] = h;
    }
}

__global__ __launch_bounds__(256) void cvt_f32_f16(
    const float4* __restrict__ src, f16x4* __restrict__ dst, int n4)
{
    int i = blockIdx.x * 256 + threadIdx.x;
    const int stride = gridDim.x * 256;
    for (; i < n4; i += stride) {
        float4 v = src[i];
        f16x4 h;
        h.x = (_Float16)v.x; h.y = (_Float16)v.y;
        h.z = (_Float16)v.z; h.w = (_Float16)v.w;
        dst[i] = h;
    }
}

// Vt[c][r] = (f16) V[r][c];  V is rows x cols (4096 x 1024)
__global__ __launch_bounds__(256) void transpose_cvt(
    const float* __restrict__ V, _Float16* __restrict__ Vt, int rows, int cols)
{
    __shared__ float tile[32][33];
    const int c0 = blockIdx.x * 32;
    const int r0 = blockIdx.y * 32;
    const int tx = threadIdx.x & 31;
    const int ty = threadIdx.x >> 5;   // 0..7
    #pragma unroll
    for (int i = 0; i < 4; ++i)
        tile[ty * 4 + i][tx] = V[(size_t)(r0 + ty * 4 + i) * cols + c0 + tx];
    __syncthreads();
    #pragma unroll
    for (int i = 0; i < 4; ++i)
        Vt[(size_t)(c0 + ty * 4 + i) * rows + r0 + tx] = (_Float16)tile[tx][ty * 4 + i];
}

extern "C" void kernel_launch(void* const* d_in, const int* in_sizes, int n_in,
                              void* d_out, int out_size, void* d_ws, size_t ws_size,
                              hipStream_t stream) {
    const float* Q = (const float*)d_in[0];
    const float* K = (const float*)d_in[1];
    const float* V = (const float*)d_in[2];
    float* out = (float*)d_out;

    const int n = 4096, m = 4096, d = 1024, vdim = 1024;
    const float scale = 0.03125f;  // 1024^-0.5

    char* w = (char*)d_ws;
    _Float16* Qh = (_Float16*)w;                        // n*d*2  = 8 MB
    _Float16* Kh = (_Float16*)(w + (8u << 20));         // 8 MB
    _Float16* Vt = (_Float16*)(w + (16u << 20));        // 8 MB
    char* rest = w + (24u << 20);
    size_t avail = ws_size > (24u << 20) ? ws_size - (24u << 20) : 0;

    int nc = 128;
    if      ((size_t)4096 * m * 6 <= avail) nc = 4096;
    else if ((size_t)2048 * m * 6 <= avail) nc = 2048;
    else if ((size_t)1024 * m * 6 <= avail) nc = 1024;
    else if ((size_t)512  * m * 6 <= avail) nc = 512;
    else if ((size_t)256  * m * 6 <= avail) nc = 256;

    float*    S = (float*)rest;                         // nc*m*4
    _Float16* P = (_Float16*)(rest + (size_t)nc * m * 4);  // nc*m*2

    cvt_f32_f16<<<dim3(2048), dim3(256), 0, stream>>>((const float4*)Q, (f16x4*)Qh, n * d / 4);
    cvt_f32_f16<<<dim3(2048), dim3(256), 0, stream>>>((const float4*)K, (f16x4*)Kh, m * d / 4);
    transpose_cvt<<<dim3(vdim / 32, m / 32), dim3(256), 0, stream>>>(V, Vt, m, vdim);

    for (int r0 = 0; r0 < n; r0 += nc) {
        gemm_bt<<<dim3(m / 128, nc / 128), dim3(256), 0, stream>>>(
            Qh + (size_t)r0 * d, Kh, S, nc, m, d);
        softmax_rows<<<dim3(nc), dim3(256), 0, stream>>>(S, P, scale);
        gemm_bt<<<dim3(vdim / 128, nc / 128), dim3(256), 0, stream>>>(
            P, Vt, out + (size_t)r0 * vdim, nc, vdim, m);
    }
}

// Round 2
// 215.590 us; speedup vs baseline: 1.1888x; 1.1888x over previous
//
#include <hip/hip_runtime.h>
#include <hip/hip_bf16.h>

typedef _Float16 f16x8 __attribute__((ext_vector_type(8)));
typedef _Float16 f16x4 __attribute__((ext_vector_type(4)));
typedef float f32x4 __attribute__((ext_vector_type(4)));

__device__ __forceinline__ void async_ld16(_Float16* lds, const _Float16* g) {
    __builtin_amdgcn_global_load_lds(
        (const __attribute__((address_space(1))) void*)g,
        (__attribute__((address_space(3))) void*)lds, 16, 0, 0);
}

// C[M,N] = A[M,K] * B[N,K]^T  (k-contiguous fp16 -> fp32), 128x128 tile,
// 4 waves 2x2, each wave 64x64 via 4x4 of 16x16x32 MFMA.
// Double-buffered LDS: one barrier per K-step; stage k+1 is issued before
// computing stage k so the ~200cyc L2 latency overlaps MFMA+ds_read.
// Split-K: blockIdx.z processes Ks of the K dim, writes partial C[z].
__global__ __launch_bounds__(256) void gemm_bt(
    const _Float16* __restrict__ A,
    const _Float16* __restrict__ B,
    float* __restrict__ C,
    int M, int N, int K, int Ks)
{
    __shared__ _Float16 At[2][128 * 32];
    __shared__ _Float16 Bt[2][128 * 32];

    const int tid  = threadIdx.x;
    const int wave = tid >> 6;
    const int lane = tid & 63;
    const int row0 = blockIdx.y * 128;
    const int col0 = blockIdx.x * 128;
    const int wr = (wave >> 1) * 64;
    const int wc = (wave & 1) * 64;
    const int quad = lane >> 4;
    const int l16  = lane & 15;

    f32x4 acc[4][4] = {};

    // staging: wave w fills LDS row-chunks w and w+4 (16 rows x 64B each);
    // lane l -> row srow, k-offset skoff (global_load_lds: base + lane*16).
    const int srow  = lane >> 2;
    const int skoff = (lane & 3) * 8;
    const size_t K64 = (size_t)64 * K;

    const _Float16* Ab = A + (size_t)row0 * K + (size_t)blockIdx.z * Ks;
    const _Float16* Bb = B + (size_t)col0 * K + (size_t)blockIdx.z * Ks;
    float* Cb = C + (size_t)blockIdx.z * M * N;

    const _Float16* pa = Ab + (size_t)(wave * 16 + srow) * K + skoff;
    const _Float16* pb = Bb + (size_t)(wave * 16 + srow) * K + skoff;

    // prologue: stage 0
    async_ld16(At[0] + wave * 512,       pa);
    async_ld16(At[0] + (wave + 4) * 512, pa + K64);
    async_ld16(Bt[0] + wave * 512,       pb);
    async_ld16(Bt[0] + (wave + 4) * 512, pb + K64);
    __syncthreads();

    int cur = 0;
    for (int k0 = 0; k0 < Ks; k0 += 32) {
        const int nxt = cur ^ 1;
        if (k0 + 32 < Ks) {
            const _Float16* qa = pa + k0 + 32;
            const _Float16* qb = pb + k0 + 32;
            async_ld16(At[nxt] + wave * 512,       qa);
            async_ld16(At[nxt] + (wave + 4) * 512, qa + K64);
            async_ld16(Bt[nxt] + wave * 512,       qb);
            async_ld16(Bt[nxt] + (wave + 4) * 512, qb + K64);
        }

        f16x8 af[4], bf[4];
        #pragma unroll
        for (int r = 0; r < 4; ++r)
            af[r] = *(const f16x8*)&At[cur][(wr + r * 16 + l16) * 32 + quad * 8];
        #pragma unroll
        for (int c = 0; c < 4; ++c)
            bf[c] = *(const f16x8*)&Bt[cur][(wc + c * 16 + l16) * 32 + quad * 8];

        #pragma unroll
        for (int r = 0; r < 4; ++r)
            #pragma unroll
            for (int c = 0; c < 4; ++c)
                acc[r][c] = __builtin_amdgcn_mfma_f32_16x16x32_f16(af[r], bf[c], acc[r][c], 0, 0, 0);

        __syncthreads();
        cur = nxt;
    }

    // C/D layout: col = lane&15, row = quad*4 + reg   [verified m89/m91]
    #pragma unroll
    for (int r = 0; r < 4; ++r) {
        const int growb = row0 + wr + r * 16 + quad * 4;
        #pragma unroll
        for (int c = 0; c < 4; ++c) {
            const int gcol = col0 + wc + c * 16 + l16;
            #pragma unroll
            for (int i = 0; i < 4; ++i)
                Cb[(size_t)(growb + i) * N + gcol] = acc[r][c][i];
        }
    }
}

// one block (256 thr) per row of S [rows x 4096]; P = softmax(S)*scale in fp16
__global__ __launch_bounds__(256) void softmax_rows(
    const float* __restrict__ S, _Float16* __restrict__ P, float scale)
{
    __shared__ float red[4];
    const int row = blockIdx.x;
    const int tid = threadIdx.x;
    const int wave = tid >> 6;
    const float4* Sr = (const float4*)(S + (size_t)row * 4096);

    float4 x[4];
    #pragma unroll
    for (int i = 0; i < 4; ++i) x[i] = Sr[tid + i * 256];

    float mx = -3.402823466e+38f;
    #pragma unroll
    for (int i = 0; i < 4; ++i)
        mx = fmaxf(mx, fmaxf(fmaxf(x[i].x, x[i].y), fmaxf(x[i].z, x[i].w)));
    #pragma unroll
    for (int off = 32; off > 0; off >>= 1) mx = fmaxf(mx, __shfl_down(mx, off));
    if ((tid & 63) == 0) red[wave] = mx;
    __syncthreads();
    mx = fmaxf(fmaxf(red[0], red[1]), fmaxf(red[2], red[3]));
    __syncthreads();

    float sum = 0.0f;
    #pragma unroll
    for (int i = 0; i < 4; ++i) {
        x[i].x = __expf(x[i].x - mx);
        x[i].y = __expf(x[i].y - mx);
        x[i].z = __expf(x[i].z - mx);
        x[i].w = __expf(x[i].w - mx);
        sum += x[i].x + x[i].y + x[i].z + x[i].w;
    }
    #pragma unroll
    for (int off = 32; off > 0; off >>= 1) sum += __shfl_down(sum, off);
    if ((tid & 63) == 0) red[wave] = sum;
    __syncthreads();
    sum = red[0] + red[1] + red[2] + red[3];

    const float inv = scale / sum;
    f16x4* Pr = (f16x4*)(P + (size_t)row * 4096);
    #pragma unroll
    for (int i = 0; i < 4; ++i) {
        f16x4 h;
        h.x = (_Float16)(x[i].x * inv);
        h.y = (_Float16)(x[i].y * inv);
        h.z = (_Float16)(x[i].z * inv);
        h.w = (_Float16)(x[i].w * inv);
        Pr[tid + i * 256] = h;
    }
}

__global__ __launch_bounds__(256) void cvt_f32_f16(
    const float4* __restrict__ src, f16x4* __restrict__ dst, int n4)
{
    int i = blockIdx.x * 256 + threadIdx.x;
    const int stride = gridDim.x * 256;
    for (; i < n4; i += stride) {
        float4 v = src[i];
        f16x4 h;
        h.x = (_Float16)v.x; h.y = (_Float16)v.y;
        h.z = (_Float16)v.z; h.w = (_Float16)v.w;
        dst[i] = h;
    }
}

// Vt[c][r] = (f16) V[r][c];  V is rows x cols
__global__ __launch_bounds__(256) void transpose_cvt(
    const float* __restrict__ V, _Float16* __restrict__ Vt, int rows, int cols)
{
    __shared__ float tile[32][33];
    const int c0 = blockIdx.x * 32;
    const int r0 = blockIdx.y * 32;
    const int tx = threadIdx.x & 31;
    const int ty = threadIdx.x >> 5;   // 0..7
    #pragma unroll
    for (int i = 0; i < 4; ++i)
        tile[ty * 4 + i][tx] = V[(size_t)(r0 + ty * 4 + i) * cols + c0 + tx];
    __syncthreads();
    #pragma unroll
    for (int i = 0; i < 4; ++i)
        Vt[(size_t)(c0 + ty * 4 + i) * rows + r0 + tx] = (_Float16)tile[tx][ty * 4 + i];
}

// out = a + b (element-wise), float4 grid-stride
__global__ __launch_bounds__(256) void reduce2(
    const float4* __restrict__ a, const float4* __restrict__ b,
    float4* __restrict__ o, int n4)
{
    int i = blockIdx.x * 256 + threadIdx.x;
    const int stride = gridDim.x * 256;
    for (; i < n4; i += stride) {
        float4 u = a[i], v = b[i];
        float4 w;
        w.x = u.x + v.x; w.y = u.y + v.y; w.z = u.z + v.z; w.w = u.w + v.w;
        o[i] = w;
    }
}

extern "C" void kernel_launch(void* const* d_in, const int* in_sizes, int n_in,
                              void* d_out, int out_size, void* d_ws, size_t ws_size,
                              hipStream_t stream) {
    const float* Q = (const float*)d_in[0];
    const float* K = (const float*)d_in[1];
    const float* V = (const float*)d_in[2];
    float* out = (float*)d_out;

    const int n = 4096, m = 4096, d = 1024, vdim = 1024;
    const float scale = 0.03125f;  // 1024^-0.5

    char* w = (char*)d_ws;
    _Float16* Qh = (_Float16*)w;                        // 8 MB
    _Float16* Kh = (_Float16*)(w + (8u << 20));         // 8 MB
    _Float16* Vt = (_Float16*)(w + (16u << 20));        // 8 MB
    char* rest = w + (24u << 20);
    size_t avail = ws_size > (24u << 20) ? ws_size - (24u << 20) : 0;

    int nc = 128;
    if      ((size_t)4096 * m * 6 <= avail) nc = 4096;
    else if ((size_t)2048 * m * 6 <= avail) nc = 2048;
    else if ((size_t)1024 * m * 6 <= avail) nc = 1024;
    else if ((size_t)512  * m * 6 <= avail) nc = 512;
    else if ((size_t)256  * m * 6 <= avail) nc = 256;

    float*    S = (float*)rest;                            // nc*m*4
    _Float16* P = (_Float16*)(rest + (size_t)nc * m * 4);  // nc*m*2
    // PV split-K partials reuse the S region (S is dead after softmax):
    // 2 * nc * vdim * 4 bytes <= nc * m * 4  (since 2*vdim <= m)  -- ok.
    float* part = S;

    cvt_f32_f16<<<dim3(2048), dim3(256), 0, stream>>>((const float4*)Q, (f16x4*)Qh, n * d / 4);
    cvt_f32_f16<<<dim3(2048), dim3(256), 0, stream>>>((const float4*)K, (f16x4*)Kh, m * d / 4);
    transpose_cvt<<<dim3(vdim / 32, m / 32), dim3(256), 0, stream>>>(V, Vt, m, vdim);

    for (int r0 = 0; r0 < n; r0 += nc) {
        // S = Qc * Kh^T   [nc x m], K-dim = d (no split)
        gemm_bt<<<dim3(m / 128, nc / 128, 1), dim3(256), 0, stream>>>(
            Qh + (size_t)r0 * d, Kh, S, nc, m, d, d);
        softmax_rows<<<dim3(nc), dim3(256), 0, stream>>>(S, P, scale);
        // part[z] = P[:, z*2048:(z+1)*2048] * Vt[:, z*2048:(z+1)*2048]^T, z=0,1
        gemm_bt<<<dim3(vdim / 128, nc / 128, 2), dim3(256), 0, stream>>>(
            P, Vt, part, nc, vdim, m, m / 2);
        // out = part[0] + part[1]
        reduce2<<<dim3(1024), dim3(256), 0, stream>>>(
            (const float4*)part, (const float4*)(part + (size_t)nc * vdim),
            (float4*)(out + (size_t)r0 * vdim), nc * vdim / 4);
    }
}

// Round 3
// 213.401 us; speedup vs baseline: 1.2010x; 1.0103x over previous
//
#include <hip/hip_runtime.h>
#include <hip/hip_bf16.h>

typedef _Float16 f16x8 __attribute__((ext_vector_type(8)));
typedef _Float16 f16x4 __attribute__((ext_vector_type(4)));
typedef float f32x4 __attribute__((ext_vector_type(4)));

__device__ __forceinline__ void async_ld16(_Float16* lds, const _Float16* g) {
    __builtin_amdgcn_global_load_lds(
        (const __attribute__((address_space(1))) void*)g,
        (__attribute__((address_space(3))) void*)lds, 16, 0, 0);
}

// C[M,N] = A[M,K] * B[N,K]^T  (k-contiguous fp16 -> fp32), 128x128 tile,
// 4 waves 2x2, each wave 64x64 via 4x4 of 16x16x32 MFMA.
// Double-buffered LDS, one barrier per K-step.
// Split-K: blockIdx.z processes Ks of K, writes partial C[z].
// 8x8 supertile swizzle: 64 consecutive block IDs cover a 1024x1024 output
// region (A-slab 2MB + B-slab 2MB at K=1024 -> fits one XCD L2), so the
// concurrently-resident window stops thrashing L2 with full-matrix slabs.
__global__ __launch_bounds__(256) void gemm_bt(
    const _Float16* __restrict__ A,
    const _Float16* __restrict__ B,
    float* __restrict__ C,
    int M, int N, int K, int Ks)
{
    __shared__ _Float16 At[2][128 * 32];
    __shared__ _Float16 Bt[2][128 * 32];

    const int tid  = threadIdx.x;
    const int wave = tid >> 6;
    const int lane = tid & 63;

    int gx = gridDim.x, gy = gridDim.y;
    int bx = blockIdx.x, by = blockIdx.y;
    if (((gx & 7) == 0) && ((gy & 7) == 0)) {
        const int bid    = bx + gx * by;
        const int ntx    = gx >> 3;          // supertiles per row
        const int sid    = bid >> 6;         // supertile id (64 blocks each)
        const int within = bid & 63;
        const int sx = sid % ntx;
        const int sy = sid / ntx;
        bx = (sx << 3) + (within & 7);
        by = (sy << 3) + (within >> 3);
    }
    const int row0 = by * 128;
    const int col0 = bx * 128;

    const int wr = (wave >> 1) * 64;
    const int wc = (wave & 1) * 64;
    const int quad = lane >> 4;
    const int l16  = lane & 15;

    f32x4 acc[4][4] = {};

    // staging: wave w fills LDS row-chunks w and w+4 (16 rows x 64B each);
    // global_load_lds dest = wave-uniform base + lane*16.
    const int srow  = lane >> 2;
    const int skoff = (lane & 3) * 8;
    const size_t K64 = (size_t)64 * K;

    const _Float16* Ab = A + (size_t)row0 * K + (size_t)blockIdx.z * Ks;
    const _Float16* Bb = B + (size_t)col0 * K + (size_t)blockIdx.z * Ks;
    float* Cb = C + (size_t)blockIdx.z * M * N;

    const _Float16* pa = Ab + (size_t)(wave * 16 + srow) * K + skoff;
    const _Float16* pb = Bb + (size_t)(wave * 16 + srow) * K + skoff;

    // prologue: stage 0
    async_ld16(At[0] + wave * 512,       pa);
    async_ld16(At[0] + (wave + 4) * 512, pa + K64);
    async_ld16(Bt[0] + wave * 512,       pb);
    async_ld16(Bt[0] + (wave + 4) * 512, pb + K64);
    __syncthreads();

    int cur = 0;
    for (int k0 = 0; k0 < Ks; k0 += 32) {
        const int nxt = cur ^ 1;
        if (k0 + 32 < Ks) {
            const _Float16* qa = pa + k0 + 32;
            const _Float16* qb = pb + k0 + 32;
            async_ld16(At[nxt] + wave * 512,       qa);
            async_ld16(At[nxt] + (wave + 4) * 512, qa + K64);
            async_ld16(Bt[nxt] + wave * 512,       qb);
            async_ld16(Bt[nxt] + (wave + 4) * 512, qb + K64);
        }

        f16x8 af[4], bf[4];
        #pragma unroll
        for (int r = 0; r < 4; ++r)
            af[r] = *(const f16x8*)&At[cur][(wr + r * 16 + l16) * 32 + quad * 8];
        #pragma unroll
        for (int c = 0; c < 4; ++c)
            bf[c] = *(const f16x8*)&Bt[cur][(wc + c * 16 + l16) * 32 + quad * 8];

        #pragma unroll
        for (int r = 0; r < 4; ++r)
            #pragma unroll
            for (int c = 0; c < 4; ++c)
                acc[r][c] = __builtin_amdgcn_mfma_f32_16x16x32_f16(af[r], bf[c], acc[r][c], 0, 0, 0);

        __syncthreads();
        cur = nxt;
    }

    // C/D layout: col = lane&15, row = quad*4 + reg   [verified m89/m91]
    #pragma unroll
    for (int r = 0; r < 4; ++r) {
        const int growb = row0 + wr + r * 16 + quad * 4;
        #pragma unroll
        for (int c = 0; c < 4; ++c) {
            const int gcol = col0 + wc + c * 16 + l16;
            #pragma unroll
            for (int i = 0; i < 4; ++i)
                Cb[(size_t)(growb + i) * N + gcol] = acc[r][c][i];
        }
    }
}

// one block (256 thr) per row of S [rows x 4096]; P = softmax(S)*scale in fp16
__global__ __launch_bounds__(256) void softmax_rows(
    const float* __restrict__ S, _Float16* __restrict__ P, float scale)
{
    __shared__ float red[4];
    const int row = blockIdx.x;
    const int tid = threadIdx.x;
    const int wave = tid >> 6;
    const float4* Sr = (const float4*)(S + (size_t)row * 4096);

    float4 x[4];
    #pragma unroll
    for (int i = 0; i < 4; ++i) x[i] = Sr[tid + i * 256];

    float mx = -3.402823466e+38f;
    #pragma unroll
    for (int i = 0; i < 4; ++i)
        mx = fmaxf(mx, fmaxf(fmaxf(x[i].x, x[i].y), fmaxf(x[i].z, x[i].w)));
    #pragma unroll
    for (int off = 32; off > 0; off >>= 1) mx = fmaxf(mx, __shfl_down(mx, off));
    if ((tid & 63) == 0) red[wave] = mx;
    __syncthreads();
    mx = fmaxf(fmaxf(red[0], red[1]), fmaxf(red[2], red[3]));
    __syncthreads();

    float sum = 0.0f;
    #pragma unroll
    for (int i = 0; i < 4; ++i) {
        x[i].x = __expf(x[i].x - mx);
        x[i].y = __expf(x[i].y - mx);
        x[i].z = __expf(x[i].z - mx);
        x[i].w = __expf(x[i].w - mx);
        sum += x[i].x + x[i].y + x[i].z + x[i].w;
    }
    #pragma unroll
    for (int off = 32; off > 0; off >>= 1) sum += __shfl_down(sum, off);
    if ((tid & 63) == 0) red[wave] = sum;
    __syncthreads();
    sum = red[0] + red[1] + red[2] + red[3];

    const float inv = scale / sum;
    f16x4* Pr = (f16x4*)(P + (size_t)row * 4096);
    #pragma unroll
    for (int i = 0; i < 4; ++i) {
        f16x4 h;
        h.x = (_Float16)(x[i].x * inv);
        h.y = (_Float16)(x[i].y * inv);
        h.z = (_Float16)(x[i].z * inv);
        h.w = (_Float16)(x[i].w * inv);
        Pr[tid + i * 256] = h;
    }
}

// convert two fp32 arrays to fp16 in one launch
__global__ __launch_bounds__(256) void cvt2_f32_f16(
    const float4* __restrict__ a, f16x4* __restrict__ da, int n4a,
    const float4* __restrict__ b, f16x4* __restrict__ db, int n4b)
{
    int i = blockIdx.x * 256 + threadIdx.x;
    const int stride = gridDim.x * 256;
    const int tot = n4a + n4b;
    for (; i < tot; i += stride) {
        const float4* s = (i < n4a) ? (a + i) : (b + (i - n4a));
        f16x4* d = (i < n4a) ? (da + i) : (db + (i - n4a));
        float4 v = *s;
        f16x4 h;
        h.x = (_Float16)v.x; h.y = (_Float16)v.y;
        h.z = (_Float16)v.z; h.w = (_Float16)v.w;
        *d = h;
    }
}

// Vt[c][r] = (f16) V[r][c];  V is rows x cols
__global__ __launch_bounds__(256) void transpose_cvt(
    const float* __restrict__ V, _Float16* __restrict__ Vt, int rows, int cols)
{
    __shared__ float tile[32][33];
    const int c0 = blockIdx.x * 32;
    const int r0 = blockIdx.y * 32;
    const int tx = threadIdx.x & 31;
    const int ty = threadIdx.x >> 5;   // 0..7
    #pragma unroll
    for (int i = 0; i < 4; ++i)
        tile[ty * 4 + i][tx] = V[(size_t)(r0 + ty * 4 + i) * cols + c0 + tx];
    __syncthreads();
    #pragma unroll
    for (int i = 0; i < 4; ++i)
        Vt[(size_t)(c0 + ty * 4 + i) * rows + r0 + tx] = (_Float16)tile[tx][ty * 4 + i];
}

// out = a + b (element-wise), float4 grid-stride
__global__ __launch_bounds__(256) void reduce2(
    const float4* __restrict__ a, const float4* __restrict__ b,
    float4* __restrict__ o, int n4)
{
    int i = blockIdx.x * 256 + threadIdx.x;
    const int stride = gridDim.x * 256;
    for (; i < n4; i += stride) {
        float4 u = a[i], v = b[i];
        float4 w;
        w.x = u.x + v.x; w.y = u.y + v.y; w.z = u.z + v.z; w.w = u.w + v.w;
        o[i] = w;
    }
}

extern "C" void kernel_launch(void* const* d_in, const int* in_sizes, int n_in,
                              void* d_out, int out_size, void* d_ws, size_t ws_size,
                              hipStream_t stream) {
    const float* Q = (const float*)d_in[0];
    const float* K = (const float*)d_in[1];
    const float* V = (const float*)d_in[2];
    float* out = (float*)d_out;

    const int n = 4096, m = 4096, d = 1024, vdim = 1024;
    const float scale = 0.03125f;  // 1024^-0.5

    char* w = (char*)d_ws;
    _Float16* Qh = (_Float16*)w;                        // 8 MB
    _Float16* Kh = (_Float16*)(w + (8u << 20));         // 8 MB
    _Float16* Vt = (_Float16*)(w + (16u << 20));        // 8 MB
    char* rest = w + (24u << 20);
    size_t avail = ws_size > (24u << 20) ? ws_size - (24u << 20) : 0;

    int nc = 128;
    if      ((size_t)4096 * m * 6 <= avail) nc = 4096;
    else if ((size_t)2048 * m * 6 <= avail) nc = 2048;
    else if ((size_t)1024 * m * 6 <= avail) nc = 1024;
    else if ((size_t)512  * m * 6 <= avail) nc = 512;
    else if ((size_t)256  * m * 6 <= avail) nc = 256;

    float*    S = (float*)rest;                            // nc*m*4
    _Float16* P = (_Float16*)(rest + (size_t)nc * m * 4);  // nc*m*2
    float* part = S;  // split-K partials reuse S (dead after softmax)

    cvt2_f32_f16<<<dim3(2048), dim3(256), 0, stream>>>(
        (const float4*)Q, (f16x4*)Qh, n * d / 4,
        (const float4*)K, (f16x4*)Kh, m * d / 4);
    transpose_cvt<<<dim3(vdim / 32, m / 32), dim3(256), 0, stream>>>(V, Vt, m, vdim);

    for (int r0 = 0; r0 < n; r0 += nc) {
        // S = Qc * Kh^T   [nc x m], K-dim = d (no split)
        gemm_bt<<<dim3(m / 128, nc / 128, 1), dim3(256), 0, stream>>>(
            Qh + (size_t)r0 * d, Kh, S, nc, m, d, d);
        softmax_rows<<<dim3(nc), dim3(256), 0, stream>>>(S, P, scale);
        // part[z] = P[:, z*2048:] * Vt[:, z*2048:]^T, z=0,1
        gemm_bt<<<dim3(vdim / 128, nc / 128, 2), dim3(256), 0, stream>>>(
            P, Vt, part, nc, vdim, m, m / 2);
        // out = part[0] + part[1]
        reduce2<<<dim3(1024), dim3(256), 0, stream>>>(
            (const float4*)part, (const float4*)(part + (size_t)nc * vdim),
            (float4*)(out + (size_t)r0 * vdim), nc * vdim / 4);
    }
}